// Round 8
// baseline (109.363 us; speedup 1.0000x reference)
//
#include <hip/hip_runtime.h>

#define NN 512
#define DD 64
#define FN 32

typedef unsigned short ushortT;
typedef __attribute__((ext_vector_type(4))) unsigned short us4;
typedef __attribute__((ext_vector_type(8))) short s8;     // 8 bf16 MFMA operand
typedef __attribute__((ext_vector_type(4))) float f4;     // MFMA accumulator

__device__ inline ushortT f2bf(float x) {
    unsigned u = __float_as_uint(x);
    return (ushortT)((u + 0x7FFFu + ((u >> 16) & 1u)) >> 16);   // RNE
}

// ---------------- Kernel P: prevT + nf bf16 + weights ----------------
// blocks 0..127: prev -> prevT bf16 (batch bk>>3, 64-row chunk bk&7)
// blocks 128..191: nf -> bf16
// block 192: W1T, W2T, v3 (v3 wave-parallel — was a 64-deep serial chain!)
__global__ __launch_bounds__(256) void prep_kernel(
    const float* __restrict__ prev, const float* __restrict__ nf,
    const float* __restrict__ W1,   const float* __restrict__ W2,
    const float* __restrict__ W3,   const float* __restrict__ W4,
    ushortT* __restrict__ prevT, ushortT* __restrict__ nfb,
    ushortT* __restrict__ W1T,   ushortT* __restrict__ W2T,
    float* __restrict__ v3)
{
    const int bk = blockIdx.x, tid = threadIdx.x;

    if (bk < 128) {                       // ---- prev transpose (one chunk)
        __shared__ float T[64][65];
        const int b = bk >> 3, c = bk & 7;
        #pragma unroll
        for (int s = 0; s < 16; ++s) {
            int idx = s * 256 + tid;
            int jl = idx >> 6, d = idx & 63;
            T[jl][d] = prev[b * NN * DD + (c * 64 + jl) * DD + d];
        }
        __syncthreads();
        #pragma unroll
        for (int s = 0; s < 16; ++s) {
            int idx = s * 256 + tid;
            int d = idx >> 6, jl = idx & 63;
            prevT[b * DD * NN + d * NN + c * 64 + jl] = f2bf(T[jl][d]);
        }
    } else if (bk < 192) {                // ---- nf convert (coalesced float4)
        const int base = (bk - 128) * 4096;
        #pragma unroll
        for (int s = 0; s < 4; ++s) {
            int i = base + s * 1024 + tid * 4;
            float4 v = *(const float4*)(nf + i);
            us4 o = { f2bf(v.x), f2bf(v.y), f2bf(v.z), f2bf(v.w) };
            *(us4*)(nfb + i) = o;
        }
    } else {                              // ---- weights
        __shared__ float vpart[4][64];
        for (int i = tid; i < DD * FN; i += 256) {      // W1T[e][f]
            int e = i >> 5, f = i & 31;
            W1T[i] = f2bf(W1[f * DD + e]);
        }
        for (int i = tid; i < DD * DD; i += 256) {      // W2T[e][d]
            int e = i >> 6, d = i & 63;
            W2T[i] = f2bf(W2[d * DD + e]);
        }
        {   // v3[e] = sum_d relu(W4[d]) * W3[d][e] — 4-way d-split, independent loads
            const int e = tid & 63, dg = tid >> 6;
            float s = 0.f;
            #pragma unroll
            for (int d0 = 0; d0 < 16; ++d0) {
                int d = dg * 16 + d0;
                s = fmaf(fmaxf(W4[d], 0.f), W3[d * DD + e], s);
            }
            vpart[dg][e] = s;
            __syncthreads();
            if (tid < 64)
                v3[tid] = vpart[0][tid] + vpart[1][tid]
                        + vpart[2][tid] + vpart[3][tid];
        }
    }
}

// ---------------- Kernel G: fused adj/ef load + t + MFMA, K split 4 ways ----------------
// (unchanged from round 7 — launched TWICE this round to measure its cost via dur_us)
#define APITCH 136            // bf16 elems per adjS row (272 B: 2-way bank alias)
#define CPITCH 68             // f32 per Cpart row (272 B)
__global__ __launch_bounds__(256) void gemm_kernel(
    const float* __restrict__ adj,   const float* __restrict__ ef,
    const ushortT* __restrict__ prevT, const ushortT* __restrict__ nfb,
    const ushortT* __restrict__ W1T, const ushortT* __restrict__ W2T,
    const float* __restrict__ v3,    float* __restrict__ out)
{
    __shared__ __align__(16) ushortT adjS[4 * 16 * APITCH];  // 17408 B
    __shared__ __align__(16) float   Cpart[4 * 16 * CPITCH]; // 17408 B
    __shared__ __align__(16) ushortT PT[16 * 72];            //  2304 B
    __shared__ float tpart[4][16];
    __shared__ float tsum[16];

    const int tid  = threadIdx.x;
    const int lane = tid & 63;
    const int w    = __builtin_amdgcn_readfirstlane(tid >> 6);
    const int i0   = blockIdx.x * 16;
    const int b    = blockIdx.x >> 5;
    const int l15  = lane & 15, g = lane >> 4;
    const int l31  = lane & 31, half = lane >> 5;

    // ---- phase A: load adj/ef fp32 (own K-slice), t-partial, convert -> LDS
    #pragma unroll
    for (int it = 0; it < 8; ++it) {
        const int r = 2 * it + half;
        const float4* a4 = (const float4*)(adj + (i0 + r) * NN + 128 * w);
        const float4* e4 = (const float4*)(ef  + (i0 + r) * NN + 128 * w);
        float4 av = a4[l31], ev = e4[l31];
        float tp = av.x*ev.x + av.y*ev.y + av.z*ev.z + av.w*ev.w;
        #pragma unroll
        for (int s = 1; s < 32; s <<= 1) tp += __shfl_xor(tp, s, 64);
        if (l31 == 0) tpart[w][r] = tp;
        us4 ov = { f2bf(av.x), f2bf(av.y), f2bf(av.z), f2bf(av.w) };
        *(us4*)(&adjS[w * 16 * APITCH + r * APITCH + 4 * l31]) = ov;
    }

    // ---- phase B: ap partial = adj_slice @ prev_slice (4 k-steps)
    f4 zero = {0.f, 0.f, 0.f, 0.f};
    f4 acc[4] = {zero, zero, zero, zero};
    const ushortT* pb = prevT + b * DD * NN + l15 * NN + 128 * w + 8 * g;
    #pragma unroll
    for (int ksl = 0; ksl < 4; ++ksl) {
        s8 A = *(const s8*)(&adjS[w * 16 * APITCH + l15 * APITCH + 32 * ksl + 8 * g]);
        #pragma unroll
        for (int nt = 0; nt < 4; ++nt) {
            s8 B = *(const s8*)(pb + nt * 16 * NN + 32 * ksl);
            acc[nt] = __builtin_amdgcn_mfma_f32_16x16x32_bf16(A, B, acc[nt], 0, 0, 0);
        }
    }

    // ---- write C partials
    #pragma unroll
    for (int nt = 0; nt < 4; ++nt)
        #pragma unroll
        for (int r = 0; r < 4; ++r)
            Cpart[w * 16 * CPITCH + (4 * g + r) * CPITCH + 16 * nt + l15] = acc[nt][r];
    __syncthreads();

    // ---- reduce C across waves -> PT (bf16, A-layout for ap@W2); reduce t
    {
        const int row = tid >> 4, c0 = (tid & 15) * 4;
        us4 o;
        #pragma unroll
        for (int c = 0; c < 4; ++c) {
            float s = Cpart[0 * 16 * CPITCH + row * CPITCH + c0 + c]
                    + Cpart[1 * 16 * CPITCH + row * CPITCH + c0 + c]
                    + Cpart[2 * 16 * CPITCH + row * CPITCH + c0 + c]
                    + Cpart[3 * 16 * CPITCH + row * CPITCH + c0 + c];
            o[c] = f2bf(s);
        }
        *(us4*)(&PT[row * 72 + c0]) = o;
        if (tid < 16)
            tsum[tid] = tpart[0][tid] + tpart[1][tid] + tpart[2][tid] + tpart[3][tid];
    }
    __syncthreads();

    // ---- epilogue: wave w owns col-tile nt = w
    float vv = v3[16 * w + l15];
    f4 o;
    #pragma unroll
    for (int r = 0; r < 4; ++r) o[r] = tsum[4 * g + r] * vv;

    s8 A1 = *(const s8*)(nfb + (i0 + l15) * FN + 8 * g);
    s8 B1 = *(const s8*)(W1T + (16 * w + l15) * FN + 8 * g);
    o = __builtin_amdgcn_mfma_f32_16x16x32_bf16(A1, B1, o, 0, 0, 0);

    #pragma unroll
    for (int k2 = 0; k2 < 2; ++k2) {
        s8 A2 = *(const s8*)(&PT[l15 * 72 + 32 * k2 + 8 * g]);
        s8 B2 = *(const s8*)(W2T + (16 * w + l15) * DD + 32 * k2 + 8 * g);
        o = __builtin_amdgcn_mfma_f32_16x16x32_bf16(A2, B2, o, 0, 0, 0);
    }

    float* orow = out + i0 * DD;
    #pragma unroll
    for (int r = 0; r < 4; ++r)
        orow[(4 * g + r) * DD + 16 * w + l15] = fmaxf(o[r], 0.f);
}

extern "C" void kernel_launch(void* const* d_in, const int* in_sizes, int n_in,
                              void* d_out, int out_size, void* d_ws, size_t ws_size,
                              hipStream_t stream) {
    const float* prev = (const float*)d_in[0];
    const float* adj  = (const float*)d_in[1];
    const float* nf   = (const float*)d_in[2];
    const float* ef   = (const float*)d_in[3];
    const float* W1   = (const float*)d_in[4];
    const float* W2   = (const float*)d_in[5];
    const float* W3   = (const float*)d_in[6];
    const float* W4   = (const float*)d_in[7];
    float* out = (float*)d_out;

    char* ws = (char*)d_ws;                                // byte offsets, 16B-aligned
    ushortT* prevT = (ushortT*)(ws + 0);                   // 1,048,576 B
    ushortT* nfb   = (ushortT*)(ws + 1048576);             //   524,288 B
    ushortT* W1T   = (ushortT*)(ws + 1572864);             //     4,096 B
    ushortT* W2T   = (ushortT*)(ws + 1576960);             //     8,192 B
    float*   v3    = (float*)  (ws + 1585152);             //       256 B

    prep_kernel<<<dim3(193), dim3(256), 0, stream>>>(
        prev, nf, W1, W2, W3, W4, prevT, nfb, W1T, W2T, v3);
    // launched twice (idempotent) — measurement: gemm cost = dur_us delta vs single
    gemm_kernel<<<dim3(512), dim3(256), 0, stream>>>(
        adj, ef, prevT, nfb, W1T, W2T, v3, out);
    gemm_kernel<<<dim3(512), dim3(256), 0, stream>>>(
        adj, ef, prevT, nfb, W1T, W2T, v3, out);
}

// Round 9
// 99.629 us; speedup vs baseline: 1.0977x; 1.0977x over previous
//
#include <hip/hip_runtime.h>

#define NN 512
#define DD 64
#define FN 32

typedef unsigned short ushortT;
typedef __attribute__((ext_vector_type(4))) unsigned short us4;
typedef __attribute__((ext_vector_type(8))) short s8;     // 8 bf16 MFMA operand
typedef __attribute__((ext_vector_type(4))) float f4;     // MFMA accumulator

__device__ inline ushortT f2bf(float x) {
    unsigned u = __float_as_uint(x);
    return (ushortT)((u + 0x7FFFu + ((u >> 16) & 1u)) >> 16);   // RNE
}

// ---------------- Kernel P: prevT + nf bf16 + weights ----------------
__global__ __launch_bounds__(256) void prep_kernel(
    const float* __restrict__ prev, const float* __restrict__ nf,
    const float* __restrict__ W1,   const float* __restrict__ W2,
    const float* __restrict__ W3,   const float* __restrict__ W4,
    ushortT* __restrict__ prevT, ushortT* __restrict__ nfb,
    ushortT* __restrict__ W1T,   ushortT* __restrict__ W2T,
    float* __restrict__ v3)
{
    const int bk = blockIdx.x, tid = threadIdx.x;

    if (bk < 128) {                       // ---- prev transpose (one 64-row chunk)
        __shared__ float T[64][65];
        const int b = bk >> 3, c = bk & 7;
        #pragma unroll
        for (int s = 0; s < 16; ++s) {
            int idx = s * 256 + tid;
            int jl = idx >> 6, d = idx & 63;
            T[jl][d] = prev[b * NN * DD + (c * 64 + jl) * DD + d];
        }
        __syncthreads();
        #pragma unroll
        for (int s = 0; s < 16; ++s) {
            int idx = s * 256 + tid;
            int d = idx >> 6, jl = idx & 63;
            prevT[b * DD * NN + d * NN + c * 64 + jl] = f2bf(T[jl][d]);
        }
    } else if (bk < 192) {                // ---- nf convert (coalesced float4)
        const int base = (bk - 128) * 4096;
        #pragma unroll
        for (int s = 0; s < 4; ++s) {
            int i = base + s * 1024 + tid * 4;
            float4 v = *(const float4*)(nf + i);
            us4 o = { f2bf(v.x), f2bf(v.y), f2bf(v.z), f2bf(v.w) };
            *(us4*)(nfb + i) = o;
        }
    } else {                              // ---- weights (v3 wave-parallel)
        __shared__ float vpart[4][64];
        for (int i = tid; i < DD * FN; i += 256) {
            int e = i >> 5, f = i & 31;
            W1T[i] = f2bf(W1[f * DD + e]);
        }
        for (int i = tid; i < DD * DD; i += 256) {
            int e = i >> 6, d = i & 63;
            W2T[i] = f2bf(W2[d * DD + e]);
        }
        {
            const int e = tid & 63, dg = tid >> 6;
            float s = 0.f;
            #pragma unroll
            for (int d0 = 0; d0 < 16; ++d0) {
                int d = dg * 16 + d0;
                s = fmaf(fmaxf(W4[d], 0.f), W3[d * DD + e], s);
            }
            vpart[dg][e] = s;
            __syncthreads();
            if (tid < 64)
                v3[tid] = vpart[0][tid] + vpart[1][tid]
                        + vpart[2][tid] + vpart[3][tid];
        }
    }
}

// ---------------- Kernel G: 8 waves/block, K split 8x64, barrier-free A/B ----------------
// 512 blocks x 512 thr; wave w owns K-slice [64w,64w+64). 4 waves/SIMD, 2 blocks/CU.
#define APITCH 520            // bf16 elems per adjS row (1040 B: 2-way bank alias on b128)
#define CPITCH 68             // f32 per Cpart row
__global__ __launch_bounds__(512, 4) void gemm_kernel(
    const float* __restrict__ adj,   const float* __restrict__ ef,
    const ushortT* __restrict__ prevT, const ushortT* __restrict__ nfb,
    const ushortT* __restrict__ W1T, const ushortT* __restrict__ W2T,
    const float* __restrict__ v3,    float* __restrict__ out)
{
    __shared__ __align__(16) ushortT adjS[16 * APITCH];      // 16640 B (full K=512 row)
    __shared__ __align__(16) float   Cpart[8 * 16 * CPITCH]; // 34816 B
    __shared__ __align__(16) ushortT PT[16 * 72];            //  2304 B
    __shared__ float tpart[8][16];
    __shared__ float tsum[16];

    const int tid  = threadIdx.x;
    const int lane = tid & 63;
    const int w    = __builtin_amdgcn_readfirstlane(tid >> 6);  // 0..7
    const int i0   = blockIdx.x * 16;
    const int b    = blockIdx.x >> 5;
    const int l15  = lane & 15, g = lane >> 4;

    // ---- phase A (no barrier): wave w loads adj/ef cols [64w,64w+64) of all 16 rows
    {
        const int r  = lane >> 2;                 // 0..15
        const int c4 = lane & 3;                  // 0..3
        const int colbase = 64 * w + 16 * c4;
        const float* ag = adj + (i0 + r) * NN + colbase;
        const float* eg = ef  + (i0 + r) * NN + colbase;
        float tp = 0.f;
        #pragma unroll
        for (int it = 0; it < 4; ++it) {
            float4 av = *(const float4*)(ag + 4 * it);
            float4 ev = *(const float4*)(eg + 4 * it);
            tp += av.x*ev.x + av.y*ev.y + av.z*ev.z + av.w*ev.w;
            us4 ov = { f2bf(av.x), f2bf(av.y), f2bf(av.z), f2bf(av.w) };
            *(us4*)(&adjS[r * APITCH + colbase + 4 * it]) = ov;
        }
        tp += __shfl_xor(tp, 1, 64);
        tp += __shfl_xor(tp, 2, 64);
        if (c4 == 0) tpart[w][r] = tp;
    }

    // ---- phase B (no barrier; own slice only): 2 k-steps x 4 n-tiles
    f4 zero = {0.f, 0.f, 0.f, 0.f};
    f4 acc[4] = {zero, zero, zero, zero};
    const ushortT* pb = prevT + b * DD * NN + l15 * NN + 64 * w + 8 * g;
    const int abase = l15 * APITCH + 64 * w + 8 * g;
    #pragma unroll
    for (int ksl = 0; ksl < 2; ++ksl) {
        s8 A = *(const s8*)(&adjS[abase + 32 * ksl]);
        #pragma unroll
        for (int nt = 0; nt < 4; ++nt) {
            s8 B = *(const s8*)(pb + nt * 16 * NN + 32 * ksl);
            acc[nt] = __builtin_amdgcn_mfma_f32_16x16x32_bf16(A, B, acc[nt], 0, 0, 0);
        }
    }

    // ---- write C partials
    #pragma unroll
    for (int nt = 0; nt < 4; ++nt)
        #pragma unroll
        for (int r = 0; r < 4; ++r)
            Cpart[w * 16 * CPITCH + (4 * g + r) * CPITCH + 16 * nt + l15] = acc[nt][r];
    __syncthreads();

    // ---- reduce C over 8 waves -> PT (bf16, A-layout); reduce t
    #pragma unroll
    for (int h = 0; h < 2; ++h) {
        int idx = h * 512 + tid;
        int row = idx >> 6, col = idx & 63;
        float s = 0.f;
        #pragma unroll
        for (int ww = 0; ww < 8; ++ww)
            s += Cpart[ww * 16 * CPITCH + row * CPITCH + col];
        PT[row * 72 + col] = f2bf(s);
    }
    if (tid < 16) {
        float s = 0.f;
        #pragma unroll
        for (int ww = 0; ww < 8; ++ww) s += tpart[ww][tid];
        tsum[tid] = s;
    }
    __syncthreads();

    // ---- epilogue: waves 0..3 own col-tile nt = w
    if (w < 4) {
        float vv = v3[16 * w + l15];
        f4 o;
        #pragma unroll
        for (int r = 0; r < 4; ++r) o[r] = tsum[4 * g + r] * vv;

        s8 A1 = *(const s8*)(nfb + (i0 + l15) * FN + 8 * g);
        s8 B1 = *(const s8*)(W1T + (16 * w + l15) * FN + 8 * g);
        o = __builtin_amdgcn_mfma_f32_16x16x32_bf16(A1, B1, o, 0, 0, 0);

        #pragma unroll
        for (int k2 = 0; k2 < 2; ++k2) {
            s8 A2 = *(const s8*)(&PT[l15 * 72 + 32 * k2 + 8 * g]);
            s8 B2 = *(const s8*)(W2T + (16 * w + l15) * DD + 32 * k2 + 8 * g);
            o = __builtin_amdgcn_mfma_f32_16x16x32_bf16(A2, B2, o, 0, 0, 0);
        }

        float* orow = out + i0 * DD;
        #pragma unroll
        for (int r = 0; r < 4; ++r)
            orow[(4 * g + r) * DD + 16 * w + l15] = fmaxf(o[r], 0.f);
    }
}

extern "C" void kernel_launch(void* const* d_in, const int* in_sizes, int n_in,
                              void* d_out, int out_size, void* d_ws, size_t ws_size,
                              hipStream_t stream) {
    const float* prev = (const float*)d_in[0];
    const float* adj  = (const float*)d_in[1];
    const float* nf   = (const float*)d_in[2];
    const float* ef   = (const float*)d_in[3];
    const float* W1   = (const float*)d_in[4];
    const float* W2   = (const float*)d_in[5];
    const float* W3   = (const float*)d_in[6];
    const float* W4   = (const float*)d_in[7];
    float* out = (float*)d_out;

    char* ws = (char*)d_ws;                                // byte offsets, 16B-aligned
    ushortT* prevT = (ushortT*)(ws + 0);                   // 1,048,576 B
    ushortT* nfb   = (ushortT*)(ws + 1048576);             //   524,288 B
    ushortT* W1T   = (ushortT*)(ws + 1572864);             //     4,096 B
    ushortT* W2T   = (ushortT*)(ws + 1576960);             //     8,192 B
    float*   v3    = (float*)  (ws + 1585152);             //       256 B

    prep_kernel<<<dim3(193), dim3(256), 0, stream>>>(
        prev, nf, W1, W2, W3, W4, prevT, nfb, W1T, W2T, v3);
    gemm_kernel<<<dim3(512), dim3(512), 0, stream>>>(
        adj, ef, prevT, nfb, W1T, W2T, v3, out);
}